// Round 5
// baseline (292.889 us; speedup 1.0000x reference)
//
#include <hip/hip_runtime.h>

#define BATCH 8
#define SLEN  2048
#define DDIM  512

typedef _Float16 f16;
typedef _Float16 half8  __attribute__((ext_vector_type(8)));
typedef _Float16 half4v __attribute__((ext_vector_type(4)));
typedef float    floatx4 __attribute__((ext_vector_type(4)));
typedef float    floatx16 __attribute__((ext_vector_type(16)));

// async global->LDS DMA, 16 B/lane; LDS dest = wave-uniform base + lane*16
__device__ __forceinline__ void gld16(const f16* g, f16* l) {
  __builtin_amdgcn_global_load_lds(
      (const __attribute__((address_space(1))) void*)g,
      (__attribute__((address_space(3))) void*)l, 16, 0, 0);
}

// pack 2 f32 -> 2 f16 in one b32 (v_cvt_pkrtz_f16_f32); builtin returns __fp16x2
__device__ __forceinline__ int pk2(float a, float b) {
  auto h = __builtin_amdgcn_cvt_pkrtz(a, b);
  union { decltype(h) v; int i; } u;
  u.v = h;
  return u.i;
}

// counted waits with compiler memory fences (loads stay in flight across barriers)
#define WAITV8() asm volatile("s_waitcnt vmcnt(8)" ::: "memory")
#define WAITV4() asm volatile("s_waitcnt vmcnt(4)" ::: "memory")
#define WAITV0() asm volatile("s_waitcnt vmcnt(0)" ::: "memory")
#define WAITL0() asm volatile("s_waitcnt lgkmcnt(0)" ::: "memory")

// raw workgroup barrier (does NOT drain vmcnt, unlike __syncthreads)
__device__ __forceinline__ void wg_barrier() {
  __builtin_amdgcn_sched_barrier(0);
  asm volatile("" ::: "memory");
  __builtin_amdgcn_s_barrier();
  asm volatile("" ::: "memory");
  __builtin_amdgcn_sched_barrier(0);
}

// ---------------- pre-pass: K -> fp16 [B][S][D], V -> fp16 transposed [B][D][S] ----------------
__global__ __launch_bounds__(256) void prep_kernel(
    const float* __restrict__ Kin, const float* __restrict__ Vin,
    f16* __restrict__ Khg, f16* __restrict__ Vtg)
{
  __shared__ f16 vt[64][264];
  const int tid = threadIdx.x;
  const int bid = blockIdx.x;
  if (bid < 2048) {
    const int base = bid * 1024 + tid;
#pragma unroll
    for (int i = 0; i < 4; ++i) {
      const int i4 = base + i * 256;
      float4 v = ((const float4*)Kin)[i4];
      half4v h;
      h.x = (f16)v.x; h.y = (f16)v.y; h.z = (f16)v.z; h.w = (f16)v.w;
      *(half4v*)(Khg + (size_t)i4 * 4) = h;
    }
  } else {
    const int vb  = bid - 2048;
    const int b   = vb >> 6;
    const int rem = vb & 63;
    const int s0  = (rem >> 3) * 256;
    const int d0  = (rem & 7) * 64;
    const float* Vb = Vin + (size_t)b * SLEN * DDIM;
    const int d4 = (tid & 15) * 4;
    const int sb = (tid >> 4) * 4;
#pragma unroll
    for (int i = 0; i < 4; ++i) {
      const int ss = sb + i * 64;
      float fa[4][4];
#pragma unroll
      for (int j = 0; j < 4; ++j) {
        float4 f = *(const float4*)(Vb + (size_t)(s0 + ss + j) * DDIM + d0 + d4);
        fa[j][0] = f.x; fa[j][1] = f.y; fa[j][2] = f.z; fa[j][3] = f.w;
      }
#pragma unroll
      for (int k = 0; k < 4; ++k) {
        half4v hv;
        hv.x = (f16)fa[0][k]; hv.y = (f16)fa[1][k];
        hv.z = (f16)fa[2][k]; hv.w = (f16)fa[3][k];
        *(half4v*)&vt[d4 + k][ss] = hv;
      }
    }
    __syncthreads();
    f16* VtB = Vtg + (size_t)b * DDIM * SLEN;
#pragma unroll
    for (int i = 0; i < 8; ++i) {
      const int c    = tid + i * 256;
      const int rd   = c >> 5;
      const int sseg = c & 31;
      *(int4*)(VtB + (size_t)(d0 + rd) * SLEN + s0 + sseg * 8) = *(const int4*)&vt[rd][sseg * 8];
    }
  }
}

// ---------------- flash attention, split-K: 256 blocks = 8 b * 16 qt * 2 kh ----------------
// r4 structure (one 512-thr block/CU, 4 wave-pairs x 32 q-rows, depth-split QK with
// S-exchange, in-register P via cvt_pkrtz+permlane32_swap, defer-max THR=8) with the
// staging schedule rebuilt as a T3/T4 counted-vmcnt pipeline:
//   - K and V double-buffered in LDS (160 KiB total, 1 block/CU)
//   - raw s_barrier (no vmcnt drain); explicit counted s_waitcnt
//   - per-wave issue order: V(kt+1) at top, K(kt+2) after bar#A
//   - pre-bar#A: lgkmcnt(0) [S-writes] + vmcnt(8)  -> drains exactly V(kt)
//   - pre-bar#B: vmcnt(8)                          -> drains exactly K(kt+1)
//   Every DMA gets a full-iteration latency window; vmcnt never hits 0 mid-loop.
//   Tail: kt=30 pre-barB vmcnt(4); kt=31 pre-barA vmcnt(0), no barB.
__global__ __launch_bounds__(512, 2) void attn_kernel(
    const float* __restrict__ Q, const f16* __restrict__ Khg,
    const f16* __restrict__ Vtg, float* __restrict__ O0,
    f16* __restrict__ O1, float* __restrict__ ML)
{
  __shared__ f16   K_l[2][32][512];    // 65,536 B [buf][key][d], rows XOR-swizzled (16B granule)
  __shared__ f16   V_l[2][4][512][8];  // 65,536 B [buf][plane=key/8][d][key%8]
  __shared__ float S_l[8][4][256];     // 32,768 B [wave][quad][lane*4]: lane-contiguous
  // total 163,840 B = 160 KiB -> 1 block/CU (8 waves)

  const int tid  = threadIdx.x;
  const int lane = tid & 63;
  const int w    = tid >> 6;      // 0..7
  const int wq   = w >> 1;        // pair: q-rows wq*32..+31 (0..3)
  const int dh   = w & 1;         // depth-half (QK) and d-half (PV out)
  const int c    = lane & 31;
  const int g    = lane >> 5;
  const int bid  = blockIdx.x;
  const int b    = bid & 7;            // batch == XCD slot
  const int qt   = (bid >> 3) & 15;
  const int kh   = bid >> 7;           // key-half
  const int q0   = qt * 128;
  const int k00  = kh * 1024;

  const f16* KhB = Khg + (size_t)b * SLEN * DDIM;
  const f16* VtB = Vtg + (size_t)b * DDIM * SLEN;

  // Q B-frags (this wave's depth-half): lane holds Q[q=c][d = dh*256 + s*16 + g*8 + j]
  half8 qf[16];
  {
    const float* Qr = Q + (size_t)(b * SLEN + q0 + wq * 32 + c) * DDIM + dh * 256 + g * 8;
#pragma unroll
    for (int s = 0; s < 16; ++s) {
      float4 f0 = *(const float4*)(Qr + s * 16);
      float4 f1 = *(const float4*)(Qr + s * 16 + 4);
      half8 hq;
      hq[0] = (f16)f0.x; hq[1] = (f16)f0.y; hq[2] = (f16)f0.z; hq[3] = (f16)f0.w;
      hq[4] = (f16)f1.x; hq[5] = (f16)f1.y; hq[6] = (f16)f1.z; hq[7] = (f16)f1.w;
      qf[s] = hq;
    }
  }

  const int swz    = (c & 7) << 4;
  const int kdh    = dh * 512;        // byte base of this wave's depth-half in a K row
  const int vplane = w >> 1;          // DMA: this wave fills plane w>>1, d-half w&1

  floatx16 o[8];                       // 32 q x 256 d (this wave's output d-half)
#pragma unroll
  for (int dt = 0; dt < 8; ++dt)
#pragma unroll
    for (int i = 0; i < 16; ++i) o[dt][i] = 0.f;
  float m_i = -3.0e38f;
  float l_i = 0.f;

  // ---- prologue: issue K(0)->buf0, V(0)->buf0, K(1)->buf1 (order = drain order) ----
#pragma unroll
  for (int i = 0; i < 4; ++i) {
    const int r = w + i * 8;
    gld16(KhB + (size_t)(k00 + r) * DDIM + (((lane << 4) ^ (w << 4)) >> 1), &K_l[0][r][0]);
  }
#pragma unroll
  for (int i = 0; i < 4; ++i) {
    const int dbase = dh * 256 + i * 64;
    gld16(VtB + (size_t)(dbase + lane) * SLEN + k00 + vplane * 8, &V_l[0][vplane][dbase][0]);
  }
#pragma unroll
  for (int i = 0; i < 4; ++i) {
    const int r = w + i * 8;
    gld16(KhB + (size_t)(k00 + 32 + r) * DDIM + (((lane << 4) ^ (w << 4)) >> 1), &K_l[1][r][0]);
  }
  WAITV8();        // drains K(0); V(0), K(1) stay in flight
  wg_barrier();

#pragma unroll 1
  for (int kt = 0; kt < 32; ++kt) {
    const f16 (*Kbuf)[512]    = K_l[kt & 1];
    const f16 (*Vbuf)[512][8] = V_l[kt & 1];

    // ---- top: issue V(kt+1) into vbuf[(kt+1)&1] (free since bar#B(kt-1)) ----
    if (kt < 31) {
      const int kv1 = k00 + (kt + 1) * 32;
      f16 (*Vdst)[512][8] = V_l[(kt + 1) & 1];
#pragma unroll
      for (int i = 0; i < 4; ++i) {
        const int dbase = dh * 256 + i * 64;
        gld16(VtB + (size_t)(dbase + lane) * SLEN + kv1 + vplane * 8, &Vdst[vplane][dbase][0]);
      }
    }

    // ---- QK^T partial: S^T[32 keys][32 q] over this wave's 256 depth ----
    const char* Krow = (const char*)&Kbuf[c][0];
    floatx16 sA;
#pragma unroll
    for (int i = 0; i < 16; ++i) sA[i] = 0.f;
    __builtin_amdgcn_s_setprio(1);
#pragma unroll
    for (int s = 0; s < 16; ++s) {
      half8 kf = *(const half8*)(Krow + ((kdh + s * 32 + g * 16) ^ swz));
      sA = __builtin_amdgcn_mfma_f32_32x32x16_f16(kf, qf[s], sA, 0, 0, 0);
    }
    __builtin_amdgcn_s_setprio(0);

    // ---- write S partial (lane-contiguous -> conflict-free) ----
#pragma unroll
    for (int j = 0; j < 4; ++j) {
      floatx4 q;
      q[0] = sA[4 * j]; q[1] = sA[4 * j + 1]; q[2] = sA[4 * j + 2]; q[3] = sA[4 * j + 3];
      *(floatx4*)&S_l[w][j][lane * 4] = q;
    }

    // ---- bar#A: S visible; own V(kt) drained (vmcnt 8 leaves K(kt+1),V(kt+1) in flight) ----
    WAITL0();
    if (kt < 31) { WAITV8(); } else { WAITV0(); }
    wg_barrier();

    // ---- add partner's partial: full S in registers ----
#pragma unroll
    for (int j = 0; j < 4; ++j) {
      floatx4 pq = *(const floatx4*)&S_l[w ^ 1][j][lane * 4];
      sA[4 * j]     += pq[0];
      sA[4 * j + 1] += pq[1];
      sA[4 * j + 2] += pq[2];
      sA[4 * j + 3] += pq[3];
    }

    // ---- online softmax, lane-local (lane owns q-row c; 16 of 32 keys) ----
    float mx = sA[0];
#pragma unroll
    for (int i = 1; i < 16; ++i) mx = fmaxf(mx, sA[i]);
    mx = fmaxf(mx, __shfl_xor(mx, 32));
    const int   up = mx > m_i + 8.0f;          // defer-max THR=8
    const float mn = up ? mx : m_i;
    const float al = up ? __expf(m_i - mn) : 1.0f;
    m_i = mn;
    float p[16], ls = 0.f;
#pragma unroll
    for (int i = 0; i < 16; ++i) { p[i] = __expf(sA[i] - m_i); ls += p[i]; }
    ls += __shfl_xor(ls, 32);
    l_i = l_i * al + ls;

    // ---- issue K(kt+2) into kbuf[kt&1] (QK(kt) readers done at bar#A) ----
    if (kt < 30) {
      f16 (*Kdst)[512] = K_l[kt & 1];
      const int kr0 = k00 + (kt + 2) * 32;
#pragma unroll
      for (int i = 0; i < 4; ++i) {
        const int r = w + i * 8;
        gld16(KhB + (size_t)(kr0 + r) * DDIM + (((lane << 4) ^ (w << 4)) >> 1), &Kdst[r][0]);
      }
    }

    // ---- P -> f16 PV A-frags in-register: cvt_pkrtz + permlane32_swap ----
    int pw[8];
#pragma unroll
    for (int j = 0; j < 8; ++j) pw[j] = pk2(p[2 * j], p[2 * j + 1]);
    asm volatile("v_permlane32_swap_b32 %0, %1" : "+v"(pw[0]), "+v"(pw[2]));
    asm volatile("v_permlane32_swap_b32 %0, %1" : "+v"(pw[1]), "+v"(pw[3]));
    asm volatile("v_permlane32_swap_b32 %0, %1" : "+v"(pw[4]), "+v"(pw[6]));
    asm volatile("v_permlane32_swap_b32 %0, %1" : "+v"(pw[5]), "+v"(pw[7]));
    union { int i[4]; half8 h; } uf0, uf1;
    uf0.i[0] = pw[0]; uf0.i[1] = pw[1]; uf0.i[2] = pw[2]; uf0.i[3] = pw[3];
    uf1.i[0] = pw[4]; uf1.i[1] = pw[5]; uf1.i[2] = pw[6]; uf1.i[3] = pw[7];
    const half8 pf0 = uf0.h, pf1 = uf1.h;

    // ---- deferred O rescale (rare): O rows are (i&3)+8*(i>>2)+4g ----
    if (__any(up)) {
#pragma unroll
      for (int i = 0; i < 16; ++i) {
        const int   ri = (i & 3) + 8 * (i >> 2) + 4 * g;
        const float fr = __shfl(al, ri);
#pragma unroll
        for (int dt = 0; dt < 8; ++dt) o[dt][i] *= fr;
      }
    }

    // ---- PV: O[32q][256d] += P(32x32) * V(32x256); V B-frag plane = 2t+g ----
    __builtin_amdgcn_s_setprio(1);
#pragma unroll
    for (int dt = 0; dt < 8; ++dt) {
      half8 vf0 = *(const half8*)&Vbuf[0 + g][dh * 256 + dt * 32 + c][0];
      half8 vf1 = *(const half8*)&Vbuf[2 + g][dh * 256 + dt * 32 + c][0];
      o[dt] = __builtin_amdgcn_mfma_f32_32x32x16_f16(pf0, vf0, o[dt], 0, 0, 0);
      o[dt] = __builtin_amdgcn_mfma_f32_32x32x16_f16(pf1, vf1, o[dt], 0, 0, 0);
    }
    __builtin_amdgcn_s_setprio(0);

    // ---- bar#B: own K(kt+1) drained (vmcnt 8 leaves V(kt+1),K(kt+2) in flight) ----
    if (kt < 31) {
      if (kt < 30) { WAITV8(); } else { WAITV4(); }
      wg_barrier();
    }
  }

  // ---- epilogue: normalize by 1/l, store ML=(m + log l, 1) so merge stays exact ----
  if (dh == 0 && g == 0) {
    const int mlb = (((kh << 3) + b) * SLEN + q0 + wq * 32 + c) * 2;
    ML[mlb]     = m_i + __logf(l_i);
    ML[mlb + 1] = 1.0f;
  }
  const float inv = 1.0f / l_i;
  const size_t rbase = (size_t)(b * SLEN + q0 + wq * 32);
#pragma unroll
  for (int i = 0; i < 16; ++i) {
    const int   ri = (i & 3) + 8 * (i >> 2) + 4 * g;
    const float fr = __shfl(inv, ri);
    const size_t ro = (rbase + ri) * DDIM + dh * 256 + c;
    if (kh == 0) {
#pragma unroll
      for (int dt = 0; dt < 8; ++dt) O0[ro + dt * 32] = o[dt][i] * fr;
    } else {
#pragma unroll
      for (int dt = 0; dt < 8; ++dt) O1[ro + dt * 32] = (f16)(o[dt][i] * fr);
    }
  }
}

// ---------------- merge: out = (w0*o0' + w1*o1') / (w0*l0 + w1*l1) ----------------
__global__ __launch_bounds__(256) void merge_kernel(
    float* __restrict__ O0, const f16* __restrict__ O1, const float* __restrict__ ML)
{
  __shared__ float wr[64][3];
  const int bid = blockIdx.x;        // 256 = b*32 + t64 (64-row tile)
  const int b = bid >> 5, t64 = bid & 31;
  const int tid = threadIdx.x;
  if (tid < 64) {
    const int row = t64 * 64 + tid;
    const int b0 = (((0 + b) * SLEN) + row) * 2;
    const int b1 = (((8 + b) * SLEN) + row) * 2;
    float m0 = ML[b0], l0 = ML[b0 + 1];
    float m1 = ML[b1], l1 = ML[b1 + 1];
    float mm = fmaxf(m0, m1);
    float w0 = __expf(m0 - mm), w1 = __expf(m1 - mm);
    wr[tid][0] = w0;
    wr[tid][1] = w1;
    wr[tid][2] = 1.0f / (w0 * l0 + w1 * l1);
  }
  __syncthreads();
  float*      Ob  = O0 + ((size_t)b * SLEN + t64 * 64) * DDIM;
  const f16*  O1b = O1 + ((size_t)b * SLEN + t64 * 64) * DDIM;
#pragma unroll 4
  for (int it = 0; it < 32; ++it) {
    const int e4 = it * 256 + tid;
    const int r  = e4 >> 7;            // 128 float4 per row
    const int d4 = (e4 & 127) * 4;
    float4 o0 = *(float4*)(Ob + (size_t)r * DDIM + d4);
    half4v o1 = *(const half4v*)(O1b + (size_t)r * DDIM + d4);
    const float w0 = wr[r][0], w1 = wr[r][1], rl = wr[r][2];
    float4 res;
    res.x = (o0.x * w0 + (float)o1.x * w1) * rl;
    res.y = (o0.y * w0 + (float)o1.y * w1) * rl;
    res.z = (o0.z * w0 + (float)o1.z * w1) * rl;
    res.w = (o0.w * w0 + (float)o1.w * w1) * rl;
    *(float4*)(Ob + (size_t)r * DDIM + d4) = res;
  }
}

extern "C" void kernel_launch(void* const* d_in, const int* in_sizes, int n_in,
                              void* d_out, int out_size, void* d_ws, size_t ws_size,
                              hipStream_t stream) {
  const float* Qp = (const float*)d_in[0];
  const float* Kp = (const float*)d_in[1];
  const float* Vp = (const float*)d_in[2];
  float* Op = (float*)d_out;

  // ws: Khg fp16 16 MiB | Vtg fp16 16 MiB | O1 fp16 16 MiB | ML fp32 256 KiB
  f16*   Khg = (f16*)d_ws;
  f16*   Vtg = (f16*)((char*)d_ws + (size_t)16777216);
  f16*   O1  = (f16*)((char*)d_ws + (size_t)33554432);
  float* ML  = (float*)((char*)d_ws + (size_t)50331648);

  prep_kernel<<<dim3(2048 + 512), dim3(256), 0, stream>>>(Kp, Vp, Khg, Vtg);
  attn_kernel<<<dim3(256), dim3(512), 0, stream>>>(Qp, Khg, Vtg, Op, O1, ML);
  merge_kernel<<<dim3(256), dim3(256), 0, stream>>>(Op, O1, ML);
}

// Round 6
// 265.269 us; speedup vs baseline: 1.1041x; 1.1041x over previous
//
#include <hip/hip_runtime.h>

#define BATCH 8
#define SLEN  2048
#define DDIM  512

typedef _Float16 f16;
typedef _Float16 half8  __attribute__((ext_vector_type(8)));
typedef _Float16 half4v __attribute__((ext_vector_type(4)));
typedef float    floatx4 __attribute__((ext_vector_type(4)));
typedef float    floatx16 __attribute__((ext_vector_type(16)));

// async global->LDS DMA, 16 B/lane; LDS dest = wave-uniform base + lane*16
__device__ __forceinline__ void gld16(const f16* g, f16* l) {
  __builtin_amdgcn_global_load_lds(
      (const __attribute__((address_space(1))) void*)g,
      (__attribute__((address_space(3))) void*)l, 16, 0, 0);
}

// pack 2 f32 -> 2 f16 in one b32 (v_cvt_pkrtz_f16_f32); builtin returns __fp16x2
__device__ __forceinline__ int pk2(float a, float b) {
  auto h = __builtin_amdgcn_cvt_pkrtz(a, b);
  union { decltype(h) v; int i; } u;
  u.v = h;
  return u.i;
}

// ---------------- pre-pass: K -> fp16 [B][S][D], V -> fp16 transposed [B][D][S] ----------------
// Rebuilt for occupancy/BW: K-part 1024 blocks, 16B half8 stores; V-part 2048 blocks
// (64x64 tiles, 8 blocks/CU) with LDS transpose. Roofline ~96 MB -> target ~15-20 us.
__global__ __launch_bounds__(256) void prep_kernel(
    const float* __restrict__ Kin, const float* __restrict__ Vin,
    f16* __restrict__ Khg, f16* __restrict__ Vtg)
{
  __shared__ f16 vt[64][72];   // [d][s] 64x64 + pad (stride 144 B)
  const int tid = threadIdx.x;
  const int bid = blockIdx.x;
  if (bid < 1024) {
    // K convert: 1024 blocks * 256 thr * 4 half8-chunks (read 2x float4, store 16B)
#pragma unroll
    for (int i = 0; i < 4; ++i) {
      const int c8 = (bid * 4 + i) * 256 + tid;     // half8 index
      float4 f0 = ((const float4*)Kin)[c8 * 2];
      float4 f1 = ((const float4*)Kin)[c8 * 2 + 1];
      half8 h;
      h[0] = (f16)f0.x; h[1] = (f16)f0.y; h[2] = (f16)f0.z; h[3] = (f16)f0.w;
      h[4] = (f16)f1.x; h[5] = (f16)f1.y; h[6] = (f16)f1.z; h[7] = (f16)f1.w;
      *(half8*)(Khg + (size_t)c8 * 8) = h;
    }
  } else {
    // V transpose: 2048 blocks = 8 b * 32 s-tiles(64) * 8 d-tiles(64)
    const int vb  = bid - 1024;
    const int b   = vb >> 8;
    const int rem = vb & 255;
    const int s0  = (rem >> 3) * 64;
    const int d0  = (rem & 7) * 64;
    const float* Vb = Vin + (size_t)b * SLEN * DDIM;
    const int d4 = (tid & 15) * 4;
    const int sb = (tid >> 4) * 4;
    float fa[4][4];
#pragma unroll
    for (int j = 0; j < 4; ++j) {
      float4 f = *(const float4*)(Vb + (size_t)(s0 + sb + j) * DDIM + d0 + d4);
      fa[j][0] = f.x; fa[j][1] = f.y; fa[j][2] = f.z; fa[j][3] = f.w;
    }
#pragma unroll
    for (int k = 0; k < 4; ++k) {
      half4v hv;
      hv.x = (f16)fa[0][k]; hv.y = (f16)fa[1][k];
      hv.z = (f16)fa[2][k]; hv.w = (f16)fa[3][k];
      *(half4v*)&vt[d4 + k][sb] = hv;   // d-row d4+k, s-cols sb..sb+3
    }
    __syncthreads();
    f16* VtB = Vtg + (size_t)b * DDIM * SLEN;
#pragma unroll
    for (int i = 0; i < 2; ++i) {
      const int c    = tid + i * 256;
      const int rd   = c >> 3;          // d-row 0..63
      const int sseg = c & 7;           // 8 int4 per row (64 s)
      *(int4*)(VtB + (size_t)(d0 + rd) * SLEN + s0 + sseg * 8) = *(const int4*)&vt[rd][sseg * 8];
    }
  }
}

// ---------------- flash attention, split-K: 256 blocks = 8 b * 16 qt * 2 kh ----------------
// (byte-identical to the verified round-4 kernel, 146 us)
// ONE 512-thread block per CU (8 waves = 4 pairs), 128 q-rows per block, shared K/V DMA.
// Pair wq owns q-rows wq*32..+31; wave dh owns depth-half dh (QK partial) and output
// d-half dh (128 acc regs). Swapped QK (mfma(A=K,B=Q)) -> S^T in C-layout, partner
// partials exchanged via lane-contiguous LDS slab across bar#A. Softmax lane-local;
// P -> f16 A-frags in-register (cvt_pkrtz + permlane32_swap); defer-max THR=8;
// epilogue normalizes by 1/l and stores ML=(m+log l, 1).
// 2-barrier phase-offset DMA skeleton:
//   top:  DMA V(kt)            drains at bar#A
//   QK_partial(kt) on K        (K(kt) DMA'd in kt-1, drained at bar#B(kt-1))
//   write S partial
//   bar#A
//   DMA K(kt+1)                drains at bar#B
//   read partner S, add, softmax+pack (registers), PV(kt) on V
//   bar#B
__global__ __launch_bounds__(512, 2) void attn_kernel(
    const float* __restrict__ Q, const f16* __restrict__ Khg,
    const f16* __restrict__ Vtg, float* __restrict__ O0,
    f16* __restrict__ O1, float* __restrict__ ML)
{
  __shared__ f16   K_l[32][512];     // 32,768 B [key][d], rows XOR-swizzled (16B granule)
  __shared__ f16   V_l[4][512][8];   // 32,768 B [plane=key/8][d][key%8]
  __shared__ float S_l[8][4][256];   // 32,768 B [wave][quad][lane*4]: lane-contiguous
  // total 98,304 B -> 1 block/CU (8 waves)

  const int tid  = threadIdx.x;
  const int lane = tid & 63;
  const int w    = tid >> 6;      // 0..7
  const int wq   = w >> 1;        // pair: q-rows wq*32..+31 (0..3)
  const int dh   = w & 1;         // depth-half (QK) and d-half (PV out)
  const int c    = lane & 31;
  const int g    = lane >> 5;
  const int bid  = blockIdx.x;
  const int b    = bid & 7;            // batch == XCD slot
  const int qt   = (bid >> 3) & 15;
  const int kh   = bid >> 7;           // key-half
  const int q0   = qt * 128;
  const int k00  = kh * 1024;

  const f16* KhB = Khg + (size_t)b * SLEN * DDIM;
  const f16* VtB = Vtg + (size_t)b * DDIM * SLEN;

  // Q B-frags (this wave's depth-half): lane holds Q[q=c][d = dh*256 + s*16 + g*8 + j]
  half8 qf[16];
  {
    const float* Qr = Q + (size_t)(b * SLEN + q0 + wq * 32 + c) * DDIM + dh * 256 + g * 8;
#pragma unroll
    for (int s = 0; s < 16; ++s) {
      float4 f0 = *(const float4*)(Qr + s * 16);
      float4 f1 = *(const float4*)(Qr + s * 16 + 4);
      half8 hq;
      hq[0] = (f16)f0.x; hq[1] = (f16)f0.y; hq[2] = (f16)f0.z; hq[3] = (f16)f0.w;
      hq[4] = (f16)f1.x; hq[5] = (f16)f1.y; hq[6] = (f16)f1.z; hq[7] = (f16)f1.w;
      qf[s] = hq;
    }
  }

  const char* Krow = (const char*)&K_l[c][0];
  const int   swz  = (c & 7) << 4;
  const int   kdh  = dh * 512;        // byte base of this wave's depth-half in a K row
  const int   vplane = w >> 1;        // DMA: this wave fills plane w>>1, d-half w&1

  floatx16 o[8];                       // 32 q x 256 d (this wave's output d-half)
#pragma unroll
  for (int dt = 0; dt < 8; ++dt)
#pragma unroll
    for (int i = 0; i < 16; ++i) o[dt][i] = 0.f;
  float m_i = -3.0e38f;
  float l_i = 0.f;

  // prologue: DMA K(0) (source pre-swizzled so linear LDS holds swizzled rows), drain
  // 8 waves x 4 rows: r = w + i*8 (r&7 == w, wave-uniform swizzle)
#pragma unroll
  for (int i = 0; i < 4; ++i) {
    const int r = w + i * 8;
    gld16(KhB + (size_t)(k00 + r) * DDIM + (((lane << 4) ^ (w << 4)) >> 1), &K_l[r][0]);
  }
  __syncthreads();

#pragma unroll 1
  for (int kt = 0; kt < 32; ++kt) {
    const int kv0 = k00 + kt * 32;
    // ---- DMA V(kt): wave fills plane w>>1, d-range (w&1)*256..+255 ----
#pragma unroll
    for (int i = 0; i < 4; ++i) {
      const int dbase = dh * 256 + i * 64;
      gld16(VtB + (size_t)(dbase + lane) * SLEN + kv0 + vplane * 8, &V_l[vplane][dbase][0]);
    }

    // ---- QK^T partial: S^T[32 keys][32 q] over this wave's 256 depth ----
    floatx16 sA;
#pragma unroll
    for (int i = 0; i < 16; ++i) sA[i] = 0.f;
    __builtin_amdgcn_s_setprio(1);
#pragma unroll
    for (int s = 0; s < 16; ++s) {
      half8 kf = *(const half8*)(Krow + ((kdh + s * 32 + g * 16) ^ swz));
      sA = __builtin_amdgcn_mfma_f32_32x32x16_f16(kf, qf[s], sA, 0, 0, 0);
    }
    __builtin_amdgcn_s_setprio(0);

    // ---- write S partial (lane-contiguous -> conflict-free) ----
#pragma unroll
    for (int j = 0; j < 4; ++j) {
      floatx4 q;
      q[0] = sA[4 * j]; q[1] = sA[4 * j + 1]; q[2] = sA[4 * j + 2]; q[3] = sA[4 * j + 3];
      *(floatx4*)&S_l[w][j][lane * 4] = q;
    }

    __syncthreads();   // bar#A: K(kt) reads done; V(kt) DMA drained; S partials visible

    // ---- DMA K(kt+1): K_l free since bar#A, drains at bar#B ----
    if (kt < 31) {
#pragma unroll
      for (int i = 0; i < 4; ++i) {
        const int r = w + i * 8;
        gld16(KhB + (size_t)(k00 + (kt + 1) * 32 + r) * DDIM
                  + (((lane << 4) ^ (w << 4)) >> 1), &K_l[r][0]);
      }
    }

    // ---- add partner's partial: full S in registers ----
#pragma unroll
    for (int j = 0; j < 4; ++j) {
      floatx4 pq = *(const floatx4*)&S_l[w ^ 1][j][lane * 4];
      sA[4 * j]     += pq[0];
      sA[4 * j + 1] += pq[1];
      sA[4 * j + 2] += pq[2];
      sA[4 * j + 3] += pq[3];
    }

    // ---- online softmax, lane-local (lane owns q-row c; 16 of 32 keys) ----
    float mx = sA[0];
#pragma unroll
    for (int i = 1; i < 16; ++i) mx = fmaxf(mx, sA[i]);
    mx = fmaxf(mx, __shfl_xor(mx, 32));
    const int   up = mx > m_i + 8.0f;          // defer-max THR=8
    const float mn = up ? mx : m_i;
    const float al = up ? __expf(m_i - mn) : 1.0f;
    m_i = mn;
    float p[16], ls = 0.f;
#pragma unroll
    for (int i = 0; i < 16; ++i) { p[i] = __expf(sA[i] - m_i); ls += p[i]; }
    ls += __shfl_xor(ls, 32);
    l_i = l_i * al + ls;

    // ---- P -> f16 PV A-frags in-register: cvt_pkrtz + permlane32_swap ----
    // reg i holds key (i&3) + 8*(i>>2) + 4g; pairs (2j,2j+1) are adjacent keys.
    int pw[8];
#pragma unroll
    for (int j = 0; j < 8; ++j) pw[j] = pk2(p[2 * j], p[2 * j + 1]);
    // After swaps: g=0 lanes hold keys 0..7 (pw[0..3]) / 16..23 (pw[4..7]);
    // g=1 lanes hold keys 8..15 / 24..31 — exact A-frag order for the two K=16 frags.
    asm volatile("v_permlane32_swap_b32 %0, %1" : "+v"(pw[0]), "+v"(pw[2]));
    asm volatile("v_permlane32_swap_b32 %0, %1" : "+v"(pw[1]), "+v"(pw[3]));
    asm volatile("v_permlane32_swap_b32 %0, %1" : "+v"(pw[4]), "+v"(pw[6]));
    asm volatile("v_permlane32_swap_b32 %0, %1" : "+v"(pw[5]), "+v"(pw[7]));
    union { int i[4]; half8 h; } uf0, uf1;
    uf0.i[0] = pw[0]; uf0.i[1] = pw[1]; uf0.i[2] = pw[2]; uf0.i[3] = pw[3];
    uf1.i[0] = pw[4]; uf1.i[1] = pw[5]; uf1.i[2] = pw[6]; uf1.i[3] = pw[7];
    const half8 pf0 = uf0.h, pf1 = uf1.h;

    // ---- deferred O rescale (rare): O rows are (i&3)+8*(i>>2)+4g ----
    if (__any(up)) {
#pragma unroll
      for (int i = 0; i < 16; ++i) {
        const int   ri = (i & 3) + 8 * (i >> 2) + 4 * g;
        const float fr = __shfl(al, ri);
#pragma unroll
        for (int dt = 0; dt < 8; ++dt) o[dt][i] *= fr;
      }
    }

    // ---- PV: O[32q][256d] += P(32x32) * V(32x256); V B-frag plane = 2t+g ----
    __builtin_amdgcn_s_setprio(1);
#pragma unroll
    for (int dt = 0; dt < 8; ++dt) {
      half8 vf0 = *(const half8*)&V_l[0 + g][dh * 256 + dt * 32 + c][0];
      half8 vf1 = *(const half8*)&V_l[2 + g][dh * 256 + dt * 32 + c][0];
      o[dt] = __builtin_amdgcn_mfma_f32_32x32x16_f16(pf0, vf0, o[dt], 0, 0, 0);
      o[dt] = __builtin_amdgcn_mfma_f32_32x32x16_f16(pf1, vf1, o[dt], 0, 0, 0);
    }
    __builtin_amdgcn_s_setprio(0);

    __syncthreads();   // bar#B: V(kt)+S reads done; K(kt+1) DMA drained
  }

  // ---- epilogue: normalize by 1/l, store ML=(m + log l, 1) so merge stays exact ----
  // ML layout: [((kh*8 + b) * SLEN + row) * 2]
  if (dh == 0 && g == 0) {
    const int mlb = (((kh << 3) + b) * SLEN + q0 + wq * 32 + c) * 2;
    ML[mlb]     = m_i + __logf(l_i);
    ML[mlb + 1] = 1.0f;
  }
  const float inv = 1.0f / l_i;
  const size_t rbase = (size_t)(b * SLEN + q0 + wq * 32);
#pragma unroll
  for (int i = 0; i < 16; ++i) {
    const int   ri = (i & 3) + 8 * (i >> 2) + 4 * g;
    const float fr = __shfl(inv, ri);
    const size_t ro = (rbase + ri) * DDIM + dh * 256 + c;
    if (kh == 0) {
#pragma unroll
      for (int dt = 0; dt < 8; ++dt) O0[ro + dt * 32] = o[dt][i] * fr;
    } else {
#pragma unroll
      for (int dt = 0; dt < 8; ++dt) O1[ro + dt * 32] = (f16)(o[dt][i] * fr);
    }
  }
}

// ---------------- merge: out = (w0*o0' + w1*o1') / (w0*l0 + w1*l1) ----------------
// Rebuilt for occupancy: 2048 blocks (8/CU), each block = 8 rows; 4 unrolled
// independent 16B-load iterations per thread. Roofline ~80 MB -> target ~15 us.
__global__ __launch_bounds__(256) void merge_kernel(
    float* __restrict__ O0, const f16* __restrict__ O1, const float* __restrict__ ML)
{
  __shared__ float wr[8][3];
  const int bid = blockIdx.x;          // 2048 = b(8) * 256 row-octs
  const int b   = bid >> 8;
  const int r0  = (bid & 255) * 8;     // first of 8 rows (within batch)
  const int tid = threadIdx.x;
  if (tid < 8) {
    const int row = r0 + tid;
    const int b0 = (((0 + b) * SLEN) + row) * 2;
    const int b1 = (((8 + b) * SLEN) + row) * 2;
    float m0 = ML[b0], l0 = ML[b0 + 1];
    float m1 = ML[b1], l1 = ML[b1 + 1];
    float mm = fmaxf(m0, m1);
    float w0 = __expf(m0 - mm), w1 = __expf(m1 - mm);
    wr[tid][0] = w0;
    wr[tid][1] = w1;
    wr[tid][2] = 1.0f / (w0 * l0 + w1 * l1);
  }
  __syncthreads();
  float*      Ob  = O0 + ((size_t)b * SLEN + r0) * DDIM;
  const f16*  O1b = O1 + ((size_t)b * SLEN + r0) * DDIM;
#pragma unroll
  for (int it = 0; it < 4; ++it) {
    const int e4 = it * 256 + tid;     // 8 rows * 128 float4
    const int r  = e4 >> 7;
    const int d4 = (e4 & 127) * 4;
    float4 o0 = *(float4*)(Ob + (size_t)r * DDIM + d4);
    half4v o1 = *(const half4v*)(O1b + (size_t)r * DDIM + d4);
    const float w0 = wr[r][0], w1 = wr[r][1], rl = wr[r][2];
    float4 res;
    res.x = (o0.x * w0 + (float)o1.x * w1) * rl;
    res.y = (o0.y * w0 + (float)o1.y * w1) * rl;
    res.z = (o0.z * w0 + (float)o1.z * w1) * rl;
    res.w = (o0.w * w0 + (float)o1.w * w1) * rl;
    *(float4*)(Ob + (size_t)r * DDIM + d4) = res;
  }
}

extern "C" void kernel_launch(void* const* d_in, const int* in_sizes, int n_in,
                              void* d_out, int out_size, void* d_ws, size_t ws_size,
                              hipStream_t stream) {
  const float* Qp = (const float*)d_in[0];
  const float* Kp = (const float*)d_in[1];
  const float* Vp = (const float*)d_in[2];
  float* Op = (float*)d_out;

  // ws: Khg fp16 16 MiB | Vtg fp16 16 MiB | O1 fp16 16 MiB | ML fp32 256 KiB
  f16*   Khg = (f16*)d_ws;
  f16*   Vtg = (f16*)((char*)d_ws + (size_t)16777216);
  f16*   O1  = (f16*)((char*)d_ws + (size_t)33554432);
  float* ML  = (float*)((char*)d_ws + (size_t)50331648);

  prep_kernel<<<dim3(1024 + 2048), dim3(256), 0, stream>>>(Kp, Vp, Khg, Vtg);
  attn_kernel<<<dim3(256), dim3(512), 0, stream>>>(Qp, Khg, Vtg, Op, O1, ML);
  merge_kernel<<<dim3(2048), dim3(256), 0, stream>>>(Op, O1, ML);
}

// Round 7
// 259.989 us; speedup vs baseline: 1.1265x; 1.0203x over previous
//
#include <hip/hip_runtime.h>

#define BATCH 8
#define SLEN  2048
#define DDIM  512

typedef _Float16 f16;
typedef _Float16 half8  __attribute__((ext_vector_type(8)));
typedef _Float16 half4v __attribute__((ext_vector_type(4)));
typedef float    floatx4 __attribute__((ext_vector_type(4)));
typedef float    floatx16 __attribute__((ext_vector_type(16)));

// async global->LDS DMA, 16 B/lane; LDS dest = wave-uniform base + lane*16
__device__ __forceinline__ void gld16(const f16* g, f16* l) {
  __builtin_amdgcn_global_load_lds(
      (const __attribute__((address_space(1))) void*)g,
      (__attribute__((address_space(3))) void*)l, 16, 0, 0);
}

// pack 2 f32 -> 2 f16 in one b32 (v_cvt_pkrtz_f16_f32); builtin returns __fp16x2
__device__ __forceinline__ int pk2(float a, float b) {
  auto h = __builtin_amdgcn_cvt_pkrtz(a, b);
  union { decltype(h) v; int i; } u;
  u.v = h;
  return u.i;
}

// counted waits; "memory" clobber = compiler fence only (no scheduling pin)
#define WAITV(n)  asm volatile("s_waitcnt vmcnt(" #n ")" ::: "memory")
#define WAITLGKM0 asm volatile("s_waitcnt lgkmcnt(0)" ::: "memory")

// raw workgroup barrier: does NOT drain vmcnt (unlike __syncthreads), and —
// unlike round-5's version — carries NO sched_barrier(0) pins (m141: those
// cost −40% by defeating the scheduler). Empty-asm clobbers fence memory ops only.
__device__ __forceinline__ void bar() {
  asm volatile("" ::: "memory");
  __builtin_amdgcn_s_barrier();
  asm volatile("" ::: "memory");
}

// ---------------- pre-pass: K -> fp16 [B][S][D], V -> fp16 transposed [B][D][S] ----------------
__global__ __launch_bounds__(256) void prep_kernel(
    const float* __restrict__ Kin, const float* __restrict__ Vin,
    f16* __restrict__ Khg, f16* __restrict__ Vtg)
{
  __shared__ f16 vt[64][72];   // [d][s] 64x64 + pad (stride 144 B)
  const int tid = threadIdx.x;
  const int bid = blockIdx.x;
  if (bid < 1024) {
    // K convert: 1024 blocks * 256 thr * 4 half8-chunks (read 2x float4, store 16B)
#pragma unroll
    for (int i = 0; i < 4; ++i) {
      const int c8 = (bid * 4 + i) * 256 + tid;     // half8 index
      float4 f0 = ((const float4*)Kin)[c8 * 2];
      float4 f1 = ((const float4*)Kin)[c8 * 2 + 1];
      half8 h;
      h[0] = (f16)f0.x; h[1] = (f16)f0.y; h[2] = (f16)f0.z; h[3] = (f16)f0.w;
      h[4] = (f16)f1.x; h[5] = (f16)f1.y; h[6] = (f16)f1.z; h[7] = (f16)f1.w;
      *(half8*)(Khg + (size_t)c8 * 8) = h;
    }
  } else {
    // V transpose: 2048 blocks = 8 b * 32 s-tiles(64) * 8 d-tiles(64)
    const int vb  = bid - 1024;
    const int b   = vb >> 8;
    const int rem = vb & 255;
    const int s0  = (rem >> 3) * 64;
    const int d0  = (rem & 7) * 64;
    const float* Vb = Vin + (size_t)b * SLEN * DDIM;
    const int d4 = (tid & 15) * 4;
    const int sb = (tid >> 4) * 4;
    float fa[4][4];
#pragma unroll
    for (int j = 0; j < 4; ++j) {
      float4 f = *(const float4*)(Vb + (size_t)(s0 + sb + j) * DDIM + d0 + d4);
      fa[j][0] = f.x; fa[j][1] = f.y; fa[j][2] = f.z; fa[j][3] = f.w;
    }
#pragma unroll
    for (int k = 0; k < 4; ++k) {
      half4v hv;
      hv.x = (f16)fa[0][k]; hv.y = (f16)fa[1][k];
      hv.z = (f16)fa[2][k]; hv.w = (f16)fa[3][k];
      *(half4v*)&vt[d4 + k][sb] = hv;   // d-row d4+k, s-cols sb..sb+3
    }
    __syncthreads();
    f16* VtB = Vtg + (size_t)b * DDIM * SLEN;
#pragma unroll
    for (int i = 0; i < 2; ++i) {
      const int c    = tid + i * 256;
      const int rd   = c >> 3;          // d-row 0..63
      const int sseg = c & 7;           // 8 int4 per row (64 s)
      *(int4*)(VtB + (size_t)(d0 + rd) * SLEN + s0 + sseg * 8) = *(const int4*)&vt[rd][sseg * 8];
    }
  }
}

// ---------------- flash attention, split-K: 256 blocks = 8 b * 16 qt * 2 kh ----------------
// r4 math/layout byte-for-byte (verified 146us, absmax 0.0390625); the ONLY change is
// the staging schedule: K and V double-buffered (160 KiB LDS, 1 block/CU, occupancy
// unchanged at 8 waves) with counted-vmcnt drains so every DMA gets a >=1-iteration
// latency window. No sched_barrier pins (r5's confound).
// Per-wave issue order (steady state, 12 loads in flight):
//   iter kt: QK(kt) on K[kt&1]; S write
//            lgkmcnt(0); vmcnt(4)  -> drains V(kt)        [K(kt+1) stays in flight]
//            bar#A
//            issue V(kt+1) -> V[(kt+1)&1]   (buffer free: PV(kt-1) done at bar#B(kt-1))
//            issue K(kt+2) -> K[kt&1]       (buffer free: QK(kt) done at bar#A(kt))
//            partner-S add, softmax, pack; PV(kt) on V[kt&1]
//            vmcnt(8)             -> drains K(kt+1)       [V(kt+1), K(kt+2) in flight]
//            bar#B
// Windows: V(kt): bar#A(kt-1) -> bar#A(kt) = 1 iter; K(kt+1): bar#A(kt-1) -> bar#B(kt)
// = 1.5 iters. Tail: kt=30 barB vmcnt(4); kt=31 barA vmcnt(0), no barB.
__global__ __launch_bounds__(512, 2) void attn_kernel(
    const float* __restrict__ Q, const f16* __restrict__ Khg,
    const f16* __restrict__ Vtg, float* __restrict__ O0,
    f16* __restrict__ O1, float* __restrict__ ML)
{
  __shared__ f16   K_l[2][32][512];    // 65,536 B [buf][key][d], rows XOR-swizzled (16B granule)
  __shared__ f16   V_l[2][4][512][8];  // 65,536 B [buf][plane=key/8][d][key%8]
  __shared__ float S_l[8][4][256];     // 32,768 B [wave][quad][lane*4]: lane-contiguous
  // total 163,840 B = 160 KiB -> 1 block/CU (8 waves)

  const int tid  = threadIdx.x;
  const int lane = tid & 63;
  const int w    = tid >> 6;      // 0..7
  const int wq   = w >> 1;        // pair: q-rows wq*32..+31 (0..3)
  const int dh   = w & 1;         // depth-half (QK) and d-half (PV out)
  const int c    = lane & 31;
  const int g    = lane >> 5;
  const int bid  = blockIdx.x;
  const int b    = bid & 7;            // batch == XCD slot
  const int qt   = (bid >> 3) & 15;
  const int kh   = bid >> 7;           // key-half
  const int q0   = qt * 128;
  const int k00  = kh * 1024;

  const f16* KhB = Khg + (size_t)b * SLEN * DDIM;
  const f16* VtB = Vtg + (size_t)b * DDIM * SLEN;

  // Q B-frags (this wave's depth-half): lane holds Q[q=c][d = dh*256 + s*16 + g*8 + j]
  half8 qf[16];
  {
    const float* Qr = Q + (size_t)(b * SLEN + q0 + wq * 32 + c) * DDIM + dh * 256 + g * 8;
#pragma unroll
    for (int s = 0; s < 16; ++s) {
      float4 f0 = *(const float4*)(Qr + s * 16);
      float4 f1 = *(const float4*)(Qr + s * 16 + 4);
      half8 hq;
      hq[0] = (f16)f0.x; hq[1] = (f16)f0.y; hq[2] = (f16)f0.z; hq[3] = (f16)f0.w;
      hq[4] = (f16)f1.x; hq[5] = (f16)f1.y; hq[6] = (f16)f1.z; hq[7] = (f16)f1.w;
      qf[s] = hq;
    }
  }

  const int swz    = (c & 7) << 4;
  const int kdh    = dh * 512;        // byte base of this wave's depth-half in a K row
  const int vplane = w >> 1;          // DMA: this wave fills plane w>>1, d-half w&1
  const int gsw    = ((lane << 4) ^ (w << 4)) >> 1;   // pre-swizzled K source offset

  floatx16 o[8];                       // 32 q x 256 d (this wave's output d-half)
#pragma unroll
  for (int dt = 0; dt < 8; ++dt)
#pragma unroll
    for (int i = 0; i < 16; ++i) o[dt][i] = 0.f;
  float m_i = -3.0e38f;
  float l_i = 0.f;

  // ---- prologue: issue K(0)->buf0 [4], V(0)->buf0 [4], K(1)->buf1 [4] ----
#pragma unroll
  for (int i = 0; i < 4; ++i) {
    const int r = w + i * 8;
    gld16(KhB + (size_t)(k00 + r) * DDIM + gsw, &K_l[0][r][0]);
  }
#pragma unroll
  for (int i = 0; i < 4; ++i) {
    const int dbase = dh * 256 + i * 64;
    gld16(VtB + (size_t)(dbase + lane) * SLEN + k00 + vplane * 8, &V_l[0][vplane][dbase][0]);
  }
#pragma unroll
  for (int i = 0; i < 4; ++i) {
    const int r = w + i * 8;
    gld16(KhB + (size_t)(k00 + 32 + r) * DDIM + gsw, &K_l[1][r][0]);
  }
  WAITV(8);        // drains K(0); V(0), K(1) stay in flight
  bar();

#pragma unroll 1
  for (int kt = 0; kt < 32; ++kt) {
    const int cur = kt & 1;

    // ---- QK^T partial: S^T[32 keys][32 q] over this wave's 256 depth ----
    const char* Krow = (const char*)&K_l[cur][c][0];
    floatx16 sA;
#pragma unroll
    for (int i = 0; i < 16; ++i) sA[i] = 0.f;
    __builtin_amdgcn_s_setprio(1);
#pragma unroll
    for (int s = 0; s < 16; ++s) {
      half8 kf = *(const half8*)(Krow + ((kdh + s * 32 + g * 16) ^ swz));
      sA = __builtin_amdgcn_mfma_f32_32x32x16_f16(kf, qf[s], sA, 0, 0, 0);
    }
    __builtin_amdgcn_s_setprio(0);

    // ---- write S partial (lane-contiguous -> conflict-free) ----
#pragma unroll
    for (int j = 0; j < 4; ++j) {
      floatx4 q;
      q[0] = sA[4 * j]; q[1] = sA[4 * j + 1]; q[2] = sA[4 * j + 2]; q[3] = sA[4 * j + 3];
      *(floatx4*)&S_l[w][j][lane * 4] = q;
    }

    // ---- bar#A: S visible (lgkm0); own V(kt) drained; K(kt+1) stays in flight ----
    WAITLGKM0;
    if (kt < 31) { WAITV(4); } else { WAITV(0); }
    bar();

    // ---- issue V(kt+1) then K(kt+2) (order matters for the vmcnt ledger) ----
    if (kt < 31) {
      const int kv1 = k00 + (kt + 1) * 32;
      f16 (*Vdst)[512][8] = V_l[cur ^ 1];
#pragma unroll
      for (int i = 0; i < 4; ++i) {
        const int dbase = dh * 256 + i * 64;
        gld16(VtB + (size_t)(dbase + lane) * SLEN + kv1 + vplane * 8, &Vdst[vplane][dbase][0]);
      }
    }
    if (kt < 30) {
      const int kr0 = k00 + (kt + 2) * 32;
      f16 (*Kdst)[512] = K_l[cur];
#pragma unroll
      for (int i = 0; i < 4; ++i) {
        const int r = w + i * 8;
        gld16(KhB + (size_t)(kr0 + r) * DDIM + gsw, &Kdst[r][0]);
      }
    }

    // ---- add partner's partial: full S in registers ----
#pragma unroll
    for (int j = 0; j < 4; ++j) {
      floatx4 pq = *(const floatx4*)&S_l[w ^ 1][j][lane * 4];
      sA[4 * j]     += pq[0];
      sA[4 * j + 1] += pq[1];
      sA[4 * j + 2] += pq[2];
      sA[4 * j + 3] += pq[3];
    }

    // ---- online softmax, lane-local (lane owns q-row c; 16 of 32 keys) ----
    float mx = sA[0];
#pragma unroll
    for (int i = 1; i < 16; ++i) mx = fmaxf(mx, sA[i]);
    mx = fmaxf(mx, __shfl_xor(mx, 32));
    const int   up = mx > m_i + 8.0f;          // defer-max THR=8
    const float mn = up ? mx : m_i;
    const float al = up ? __expf(m_i - mn) : 1.0f;
    m_i = mn;
    float p[16], ls = 0.f;
#pragma unroll
    for (int i = 0; i < 16; ++i) { p[i] = __expf(sA[i] - m_i); ls += p[i]; }
    ls += __shfl_xor(ls, 32);
    l_i = l_i * al + ls;

    // ---- P -> f16 PV A-frags in-register: cvt_pkrtz + permlane32_swap ----
    // reg i holds key (i&3) + 8*(i>>2) + 4g; pairs (2j,2j+1) are adjacent keys.
    int pw[8];
#pragma unroll
    for (int j = 0; j < 8; ++j) pw[j] = pk2(p[2 * j], p[2 * j + 1]);
    // After swaps: g=0 lanes hold keys 0..7 (pw[0..3]) / 16..23 (pw[4..7]);
    // g=1 lanes hold keys 8..15 / 24..31 — exact A-frag order for the two K=16 frags.
    asm volatile("v_permlane32_swap_b32 %0, %1" : "+v"(pw[0]), "+v"(pw[2]));
    asm volatile("v_permlane32_swap_b32 %0, %1" : "+v"(pw[1]), "+v"(pw[3]));
    asm volatile("v_permlane32_swap_b32 %0, %1" : "+v"(pw[4]), "+v"(pw[6]));
    asm volatile("v_permlane32_swap_b32 %0, %1" : "+v"(pw[5]), "+v"(pw[7]));
    union { int i[4]; half8 h; } uf0, uf1;
    uf0.i[0] = pw[0]; uf0.i[1] = pw[1]; uf0.i[2] = pw[2]; uf0.i[3] = pw[3];
    uf1.i[0] = pw[4]; uf1.i[1] = pw[5]; uf1.i[2] = pw[6]; uf1.i[3] = pw[7];
    const half8 pf0 = uf0.h, pf1 = uf1.h;

    // ---- deferred O rescale (rare): O rows are (i&3)+8*(i>>2)+4g ----
    if (__any(up)) {
#pragma unroll
      for (int i = 0; i < 16; ++i) {
        const int   ri = (i & 3) + 8 * (i >> 2) + 4 * g;
        const float fr = __shfl(al, ri);
#pragma unroll
        for (int dt = 0; dt < 8; ++dt) o[dt][i] *= fr;
      }
    }

    // ---- PV: O[32q][256d] += P(32x32) * V(32x256); V B-frag plane = 2t+g ----
    __builtin_amdgcn_s_setprio(1);
#pragma unroll
    for (int dt = 0; dt < 8; ++dt) {
      half8 vf0 = *(const half8*)&V_l[cur][0 + g][dh * 256 + dt * 32 + c][0];
      half8 vf1 = *(const half8*)&V_l[cur][2 + g][dh * 256 + dt * 32 + c][0];
      o[dt] = __builtin_amdgcn_mfma_f32_32x32x16_f16(pf0, vf0, o[dt], 0, 0, 0);
      o[dt] = __builtin_amdgcn_mfma_f32_32x32x16_f16(pf1, vf1, o[dt], 0, 0, 0);
    }
    __builtin_amdgcn_s_setprio(0);

    // ---- bar#B: own K(kt+1) drained; V(kt+1), K(kt+2) stay in flight ----
    if (kt < 31) {
      if (kt < 30) { WAITV(8); } else { WAITV(4); }
      bar();
    }
  }

  // ---- epilogue: normalize by 1/l, store ML=(m + log l, 1) so merge stays exact ----
  if (dh == 0 && g == 0) {
    const int mlb = (((kh << 3) + b) * SLEN + q0 + wq * 32 + c) * 2;
    ML[mlb]     = m_i + __logf(l_i);
    ML[mlb + 1] = 1.0f;
  }
  const float inv = 1.0f / l_i;
  const size_t rbase = (size_t)(b * SLEN + q0 + wq * 32);
#pragma unroll
  for (int i = 0; i < 16; ++i) {
    const int   ri = (i & 3) + 8 * (i >> 2) + 4 * g;
    const float fr = __shfl(inv, ri);
    const size_t ro = (rbase + ri) * DDIM + dh * 256 + c;
    if (kh == 0) {
#pragma unroll
      for (int dt = 0; dt < 8; ++dt) O0[ro + dt * 32] = o[dt][i] * fr;
    } else {
#pragma unroll
      for (int dt = 0; dt < 8; ++dt) O1[ro + dt * 32] = (f16)(o[dt][i] * fr);
    }
  }
}

// ---------------- merge: out = (w0*o0' + w1*o1') / (w0*l0 + w1*l1) ----------------
__global__ __launch_bounds__(256) void merge_kernel(
    float* __restrict__ O0, const f16* __restrict__ O1, const float* __restrict__ ML)
{
  __shared__ float wr[8][3];
  const int bid = blockIdx.x;          // 2048 = b(8) * 256 row-octs
  const int b   = bid >> 8;
  const int r0  = (bid & 255) * 8;     // first of 8 rows (within batch)
  const int tid = threadIdx.x;
  if (tid < 8) {
    const int row = r0 + tid;
    const int b0 = (((0 + b) * SLEN) + row) * 2;
    const int b1 = (((8 + b) * SLEN) + row) * 2;
    float m0 = ML[b0], l0 = ML[b0 + 1];
    float m1 = ML[b1], l1 = ML[b1 + 1];
    float mm = fmaxf(m0, m1);
    float w0 = __expf(m0 - mm), w1 = __expf(m1 - mm);
    wr[tid][0] = w0;
    wr[tid][1] = w1;
    wr[tid][2] = 1.0f / (w0 * l0 + w1 * l1);
  }
  __syncthreads();
  float*      Ob  = O0 + ((size_t)b * SLEN + r0) * DDIM;
  const f16*  O1b = O1 + ((size_t)b * SLEN + r0) * DDIM;
#pragma unroll
  for (int it = 0; it < 4; ++it) {
    const int e4 = it * 256 + tid;     // 8 rows * 128 float4
    const int r  = e4 >> 7;
    const int d4 = (e4 & 127) * 4;
    float4 o0 = *(float4*)(Ob + (size_t)r * DDIM + d4);
    half4v o1 = *(const half4v*)(O1b + (size_t)r * DDIM + d4);
    const float w0 = wr[r][0], w1 = wr[r][1], rl = wr[r][2];
    float4 res;
    res.x = (o0.x * w0 + (float)o1.x * w1) * rl;
    res.y = (o0.y * w0 + (float)o1.y * w1) * rl;
    res.z = (o0.z * w0 + (float)o1.z * w1) * rl;
    res.w = (o0.w * w0 + (float)o1.w * w1) * rl;
    *(float4*)(Ob + (size_t)r * DDIM + d4) = res;
  }
}

extern "C" void kernel_launch(void* const* d_in, const int* in_sizes, int n_in,
                              void* d_out, int out_size, void* d_ws, size_t ws_size,
                              hipStream_t stream) {
  const float* Qp = (const float*)d_in[0];
  const float* Kp = (const float*)d_in[1];
  const float* Vp = (const float*)d_in[2];
  float* Op = (float*)d_out;

  // ws: Khg fp16 16 MiB | Vtg fp16 16 MiB | O1 fp16 16 MiB | ML fp32 256 KiB
  f16*   Khg = (f16*)d_ws;
  f16*   Vtg = (f16*)((char*)d_ws + (size_t)16777216);
  f16*   O1  = (f16*)((char*)d_ws + (size_t)33554432);
  float* ML  = (float*)((char*)d_ws + (size_t)50331648);

  prep_kernel<<<dim3(1024 + 2048), dim3(256), 0, stream>>>(Kp, Vp, Khg, Vtg);
  attn_kernel<<<dim3(256), dim3(512), 0, stream>>>(Qp, Khg, Vtg, Op, O1, ML);
  merge_kernel<<<dim3(2048), dim3(256), 0, stream>>>(Op, O1, ML);
}